// Round 1
// baseline (43.822 us; speedup 1.0000x reference)
//
#include <hip/hip_runtime.h>

// LIF forward scan over T=16, one thread per 4 neurons, float4 I/O.
// x_seq: [B=32, T=16, C=64, H=32, W=32] fp32; out: same shape, fp32 spikes.
// Layout: elem(b,t,sp) = b*(T*S) + t*S + sp, S = 64*32*32 = 65536.
// In float4 units: S4 = 16384 groups/timestep, per-batch = T*S4 = 262144.

#define LIF_T      16
#define LIF_S4     16384           // spatial float4-groups per (b,t)
#define LIF_BETA   0.9f
#define LIF_VTH    1.0f

__global__ __launch_bounds__(256)
void LIFNodeSTBP_63513976373966_kernel(const float4* __restrict__ x,
                                       float4* __restrict__ out)
{
    const int g  = blockIdx.x * blockDim.x + threadIdx.x;   // [0, B*S4)
    const int b  = g >> 14;          // g / LIF_S4
    const int sp = g & (LIF_S4 - 1); // g % LIF_S4
    const size_t base = (size_t)b * (LIF_T * LIF_S4) + (size_t)sp;

    float4 v = make_float4(0.0f, 0.0f, 0.0f, 0.0f);

#pragma unroll
    for (int t = 0; t < LIF_T; ++t) {
        const size_t idx = base + (size_t)t * LIF_S4;
        const float4 xv = x[idx];

        v.x = v.x * LIF_BETA + xv.x;
        v.y = v.y * LIF_BETA + xv.y;
        v.z = v.z * LIF_BETA + xv.z;
        v.w = v.w * LIF_BETA + xv.w;

        const float sx = (v.x >= LIF_VTH) ? 1.0f : 0.0f;
        const float sy = (v.y >= LIF_VTH) ? 1.0f : 0.0f;
        const float sz = (v.z >= LIF_VTH) ? 1.0f : 0.0f;
        const float sw = (v.w >= LIF_VTH) ? 1.0f : 0.0f;

        v.x -= sx * LIF_VTH;
        v.y -= sy * LIF_VTH;
        v.z -= sz * LIF_VTH;
        v.w -= sw * LIF_VTH;

        out[idx] = make_float4(sx, sy, sz, sw);
    }
}

extern "C" void kernel_launch(void* const* d_in, const int* in_sizes, int n_in,
                              void* d_out, int out_size, void* d_ws, size_t ws_size,
                              hipStream_t stream)
{
    const float4* x = (const float4*)d_in[0];
    float4* out = (float4*)d_out;

    // total elements = 32*16*64*32*32 = 33,554,432; float4 groups = 8,388,608
    // threads = groups / T? No: each thread owns 4 neurons across all T.
    // neuron float4-groups total = B * S4 = 32 * 16384 = 524288 threads.
    const int n_threads = (in_sizes[0] / LIF_T) / 4;  // 524288
    const int block = 256;
    const int grid = (n_threads + block - 1) / block; // 2048

    LIFNodeSTBP_63513976373966_kernel<<<grid, block, 0, stream>>>(x, out);
}